// Round 12
// baseline (10561.430 us; speedup 1.0000x reference)
//
#include <hip/hip_runtime.h>
#include <hip/hip_fp16.h>
#include <cstdint>
#include <cstddef>

// ---------------------------------------------------------------------------
// Fused cross-modal 2-layer LSTM, B=256, S=128, H=1024, 3 modalities.
// v12: concurrency attack. Model from 11 rounds: miss-path BW ~0.7 GB/s per
// resident WAVE; previous grids supplied only 12 waves/CU (grid-limited, not
// VGPR-limited). v12: M-tile 32, grid = 3*64*8mt = 1536 blocks = 6 blocks/CU
// (launch_bounds(256,6)), 16 KB LDS/block, 24 waves/CU. Internals = v7:
// K-split-4 over K128 tiles, frag-packed B global->VGPR (2 sets,
// syncthreads dbuf), cross-wave LDS reduction, fused LSTM cell epilogue.
// fp16 MFMA fp32-accum. Multi-launch 2 dispatches/step.
// ---------------------------------------------------------------------------

typedef _Float16 half8 __attribute__((ext_vector_type(8)));
typedef float floatx4 __attribute__((ext_vector_type(4)));

__device__ __forceinline__ void gload16(const void* g, void* l) {
  __builtin_amdgcn_global_load_lds(
      (const __attribute__((address_space(1))) void*)g,
      (__attribute__((address_space(3))) void*)l, 16, 0, 0);
}
__device__ __forceinline__ float fsig(float x) {
  return 1.f / (1.f + __expf(-x));
}
__device__ __forceinline__ float ftanhf(float x) {
  x = fminf(15.f, fmaxf(-15.f, x));
  float e = __expf(2.f * x);
  return (e - 1.f) / (e + 1.f);
}

struct ModParam {
  const __half* xseg;   // chunked [Kx/8][256][8] (null if Kx==0)
  const __half* inseg;  // chunked [Kin/8][256][8]
  const __half* W;      // frag-packed [64][nKt][4 wid][4 ni][64 lane][8]
  const float* bias;    // [4096] gate-interleaved (bih+bhh)
  float* c;             // [256][1024] fp32 cell state
  __half* dst0; __half* dst1; __half* dst2;  // chunked h dests (may be null)
  int off0, off1, off2; // column offsets (multiples of 1024)
  __half* feat; int featoff;  // linear [256][3072]; last step only
  int Kx, Kin;
};
struct PhaseParams { ModParam m[3]; };

// C[b,n'] = sum_k In[b,k] * W[n',k];  M=256, N=4096 per modality.
// Block = 32(M) x 64(N); 4 waves K-split a K128 staged tile (wave w takes
// k-quarter w); 2x4 16x16x32 fragments per wave; LDS reduce; fused cell.
// grid = 8 xcd-slots * 192 = 1536 blocks = 6 blocks/CU (24 waves/CU).
__global__ __launch_bounds__(256, 6) void lstm_phase(PhaseParams P) {
  const int b_ = blockIdx.x;
  const int xcd = b_ & 7, rnd = b_ >> 3;       // 8 slots x 192 rounds
  const int pairIdx = xcd * 24 + (rnd >> 3);   // 0..191 = (mod, bn)
  const int mt = rnd & 7;                      // 8 M-tiles of 32 rows
  const int mod = pairIdx >> 6;
  const int bn = pairIdx & 63;
  const ModParam p = P.m[mod];
  const int nKt = (p.Kx + p.Kin) >> 7;
  const int KxT = p.Kx >> 7;
  const int tid = threadIdx.x;
  const int lane = tid & 63, wid = tid >> 6;
  const int ln = lane & 15, lm = lane >> 4, c4 = lane & 3;

  __shared__ __align__(16) __half smem[2][512][8];  // 16 KiB (2 A-buffers)

  floatx4 acc[2][4];
#pragma unroll
  for (int a = 0; a < 2; ++a)
#pragma unroll
    for (int b = 0; b < 4; ++b) acc[a][b] = (floatx4)0.f;

  half8 bvA[4], bvB[4];

  auto stageA = [&](int kt, int buf) {
    const __half* base; int kq0;
    if (kt < KxT) { base = p.xseg;  kq0 = kt * 16; }
    else          { base = p.inseg; kq0 = (kt - KxT) * 16; }
#pragma unroll
    for (int it = 0; it < 2; ++it) {
      int idx = it * 256 + tid;                 // chunk id 0..511
      int kql = idx >> 5, row = idx & 31;       // 16 kq x 32 rows
      gload16(base + ((size_t)(kq0 + kql) * 256 + mt * 32 + row) * 8,
              &smem[buf][idx][0]);
    }
  };
  auto loadB = [&](int kt, half8 (&bv)[4]) {
    const __half* src =
        p.W + ((size_t)(bn * nKt + kt) * 4 + wid) * 2048 + lane * 8;
#pragma unroll
    for (int ni = 0; ni < 4; ++ni) bv[ni] = *(const half8*)(src + ni * 512);
  };
  auto compute = [&](int buf, const half8 (&bv)[4]) {
    half8 av[2];
    const int kq = wid * 4 + lm;                // wave's k-quarter chunk
#pragma unroll
    for (int mi = 0; mi < 2; ++mi)
      av[mi] = *(const half8*)&smem[buf][kq * 32 + mi * 16 + ln][0];
#pragma unroll
    for (int mi = 0; mi < 2; ++mi)
#pragma unroll
      for (int ni = 0; ni < 4; ++ni)
        acc[mi][ni] = __builtin_amdgcn_mfma_f32_16x16x32_f16(
            av[mi], bv[ni], acc[mi][ni], 0, 0, 0);
  };

  loadB(0, bvA);
  stageA(0, 0);
  __syncthreads();
  int kt = 0;
  while (true) {
    if (kt + 1 < nKt) { loadB(kt + 1, bvB); stageA(kt + 1, 1); }
    compute(0, bvA);
    __syncthreads();
    if (++kt >= nKt) break;
    if (kt + 1 < nKt) { loadB(kt + 1, bvA); stageA(kt + 1, 0); }
    compute(1, bvB);
    __syncthreads();
    if (++kt >= nKt) break;
  }

  // ---- cross-wave K-reduction (acc summed over the 4 waves) ----
  // rbuf[ni(4)][w(4)][lane(64)] of floatx4 = 16 KiB (reuses smem).
  // Round mi: all waves store acc[mi][*]; wave w then owns ni==w.
  floatx4* rbuf = (floatx4*)&smem[0][0][0];
  auto slot = [&](int ni, int w) { return (ni * 4 + w) * 64 + lane; };
  floatx4 own[2];
#pragma unroll
  for (int mi = 0; mi < 2; ++mi) {
    __syncthreads();
#pragma unroll
    for (int ni = 0; ni < 4; ++ni) rbuf[slot(ni, wid)] = acc[mi][ni];
    __syncthreads();
    own[mi] = rbuf[slot(wid, 0)] + rbuf[slot(wid, 1)] + rbuf[slot(wid, 2)] +
              rbuf[slot(wid, 3)];
  }

  // ---- fused LSTM cell epilogue (wave owns N-cols [wid*16, wid*16+16)) ---
  const int ncol = bn * 64 + wid * 16 + ln;
  const float bia = p.bias[ncol];
  const int j = ncol >> 2;
#pragma unroll
  for (int mi = 0; mi < 2; ++mi) {
#pragma unroll
    for (int r = 0; r < 4; ++r) {
      float v = own[mi][r] + bia;
      float g1 = __shfl_xor(v, 1);
      float g2 = __shfl_xor(v, 2);
      float g3 = __shfl_xor(v, 3);
      int m0 = c4, m1 = c4 ^ 1, m2 = c4 ^ 2, m3 = c4 ^ 3;
      float zi = m0 == 0 ? v : (m0 == 1 ? g1 : (m0 == 2 ? g2 : g3));
      float zf = m1 == 0 ? v : (m1 == 1 ? g1 : (m1 == 2 ? g2 : g3));
      float zg = m2 == 0 ? v : (m2 == 1 ? g1 : (m2 == 2 ? g2 : g3));
      float zo = m3 == 0 ? v : (m3 == 1 ? g1 : (m3 == 2 ? g2 : g3));
      const int b = mt * 32 + mi * 16 + lm * 4 + r;
      float cp = p.c[b * 1024 + j];
      float cn = fsig(zf) * cp + fsig(zi) * ftanhf(zg);
      float hn = fsig(zo) * ftanhf(cn);
      __half h16 = __float2half(hn);
      if (c4 == 0) {
        if (p.dst0) {
          int col = p.off0 + j;
          p.dst0[(size_t)(col >> 3) * 2048 + b * 8 + (col & 7)] = h16;
        }
      } else if (c4 == 1) {
        if (p.dst1) {
          int col = p.off1 + j;
          p.dst1[(size_t)(col >> 3) * 2048 + b * 8 + (col & 7)] = h16;
        }
      } else if (c4 == 2) {
        if (p.dst2) {
          int col = p.off2 + j;
          p.dst2[(size_t)(col >> 3) * 2048 + b * 8 + (col & 7)] = h16;
        }
      } else {
        p.c[b * 1024 + j] = cn;
        if (p.feat) p.feat[(size_t)b * 3072 + p.featoff + j] = h16;
      }
    }
  }
}

// Repack weights fp32->fp16 into MFMA-fragment order (unchanged from v7):
// dst[((nt*nKt + kt)*4 + wid)*2048 + ni*512 + lane*8 + e] = W[n][k], where
// n = nt*64 + ni*16 + (lane&15) (gate-interleaved src), k = kt*128 + wid*32
// + (lane>>4)*8 + e, columns = [x pad fpad | ih-h (hih) | hh 1024].
__global__ void pack_w(__half* dst, const float* Wih, const float* Whh,
                       float* bdst, const float* bih, const float* bhh,
                       int f, int fpad, int hih, int Ktot) {
  long long i = (long long)blockIdx.x * 256 + threadIdx.x;
  long long tot = (long long)4096 * Ktot;
  const int nKt = Ktot >> 7;
  if (i < tot) {
    int q = (int)(i >> 11);
    int wid = q & 3;
    int p2 = q >> 2;
    int ktile = p2 % nKt, nt = p2 / nKt;
    int r = (int)(i & 2047);
    int ni = r >> 9, lane = (r >> 3) & 63, e = r & 7;
    int n = nt * 64 + ni * 16 + (lane & 15);
    int nsrc = (n & 3) * 1024 + (n >> 2);
    int k = ktile * 128 + wid * 32 + (lane >> 4) * 8 + e;
    float v;
    if (k < fpad)
      v = (k < f) ? Wih[(size_t)nsrc * (f + hih) + k] : 0.f;
    else if (k < fpad + hih)
      v = Wih[(size_t)nsrc * (f + hih) + f + (k - fpad)];
    else
      v = Whh[(size_t)nsrc * 1024 + (k - fpad - hih)];
    dst[i] = __float2half(v);
  }
  if (i < 4096) {
    int nsrc = ((int)i & 3) * 1024 + ((int)i >> 2);
    bdst[i] = bih[nsrc] + bhh[nsrc];
  }
}

// x [B=256][S=128][f] fp32 -> chunked fp16 [S][fpad/8][256][8], zero-padded.
__global__ void pack_x(__half* dst, const float* x, int f, int fpad) {
  long long i = (long long)blockIdx.x * 256 + threadIdx.x;
  long long tot = (long long)128 * 256 * fpad;
  if (i >= tot) return;
  int e = (int)(i & 7);
  long long u = i >> 3;
  int b = (int)(u & 255);
  long long v = u >> 8;
  int nq = fpad >> 3;
  int kq = (int)(v % nq);
  int t = (int)(v / nq);
  int k = kq * 8 + e;
  dst[i] = (k < f) ? __float2half(x[((size_t)b * 128 + t) * f + k])
                   : __float2half(0.f);
}

// out[b] = feat[b,:] . Wd + bd
__global__ void final_dot(const __half* feat, const float* Wd, const float* bd,
                          float* out) {
  int b = blockIdx.x, tid = threadIdx.x;
  float s = 0.f;
  for (int j = tid; j < 3072; j += 256)
    s += __half2float(feat[(size_t)b * 3072 + j]) * Wd[j];
  __shared__ float red[256];
  red[tid] = s;
  __syncthreads();
  for (int o = 128; o > 0; o >>= 1) {
    if (tid < o) red[tid] += red[tid + o];
    __syncthreads();
  }
  if (tid == 0) out[b] = red[0] + bd[0];
}

extern "C" void kernel_launch(void* const* d_in, const int* in_sizes, int n_in,
                              void* d_out, int out_size, void* d_ws, size_t ws_size,
                              hipStream_t stream) {
  const int B = 256, S = 128, H = 1024, NG = 4096;
  const int FRAW[3] = {300, 35, 74};
  const int FPAD[3] = {384, 128, 128};  // multiples of 128

  const float* xin[3] = {(const float*)d_in[0], (const float*)d_in[1],
                         (const float*)d_in[2]};
  const float *Wih0[3], *Whh0[3], *bih0[3], *bhh0[3];
  const float *Wih1[3], *Whh1[3], *bih1[3], *bhh1[3];
  for (int m = 0; m < 3; ++m) {
    int bidx = 3 + m * 8;
    Wih0[m] = (const float*)d_in[bidx + 0];
    Whh0[m] = (const float*)d_in[bidx + 1];
    bih0[m] = (const float*)d_in[bidx + 2];
    bhh0[m] = (const float*)d_in[bidx + 3];
    Wih1[m] = (const float*)d_in[bidx + 4];
    Whh1[m] = (const float*)d_in[bidx + 5];
    bih1[m] = (const float*)d_in[bidx + 6];
    bhh1[m] = (const float*)d_in[bidx + 7];
  }
  const float* Wd = (const float*)d_in[27];
  const float* bd = (const float*)d_in[28];

  uint8_t* wsb = (uint8_t*)d_ws;
  size_t off = 0;
  auto alloc = [&](size_t bytes) -> void* {
    void* p = wsb + off;
    off += (bytes + 255) & ~(size_t)255;
    return p;
  };

  __half* W0[3];
  __half* W1[3];
  int K0[3];
  for (int m = 0; m < 3; ++m) {
    K0[m] = FPAD[m] + 3 * H;
    W0[m] = (__half*)alloc((size_t)NG * K0[m] * 2);
  }
  for (int m = 0; m < 3; ++m) W1[m] = (__half*)alloc((size_t)NG * 2 * H * 2);
  float* biasB = (float*)alloc((size_t)6 * NG * 4);
  __half* X16[3];
  for (int m = 0; m < 3; ++m)
    X16[m] = (__half*)alloc((size_t)S * B * FPAD[m] * 2);
  size_t stateStart = off;
  __half* In0[3];
  __half* In1[3];
  for (int m = 0; m < 3; ++m) In0[m] = (__half*)alloc((size_t)2 * B * 3072 * 2);
  for (int m = 0; m < 3; ++m) In1[m] = (__half*)alloc((size_t)2 * B * 2048 * 2);
  float* cbuf = (float*)alloc((size_t)6 * B * H * 4);
  size_t stateEnd = off;
  __half* featB = (__half*)alloc((size_t)B * 3072 * 2);

  if (off > ws_size) return;

  // ---- one-time prep (every call; deterministic) ----
  for (int m = 0; m < 3; ++m) {
    long long tot0 = (long long)NG * K0[m];
    pack_w<<<dim3((unsigned)((tot0 + 255) / 256)), 256, 0, stream>>>(
        W0[m], Wih0[m], Whh0[m], biasB + m * NG, bih0[m], bhh0[m],
        FRAW[m], FPAD[m], 2 * H, K0[m]);
    long long tot1 = (long long)NG * 2 * H;
    pack_w<<<dim3((unsigned)((tot1 + 255) / 256)), 256, 0, stream>>>(
        W1[m], Wih1[m], Whh1[m], biasB + (3 + m) * NG, bih1[m], bhh1[m],
        0, 0, H, 2 * H);
    long long totx = (long long)S * B * FPAD[m];
    pack_x<<<dim3((unsigned)((totx + 255) / 256)), 256, 0, stream>>>(
        X16[m], xin[m], FRAW[m], FPAD[m]);
  }
  hipMemsetAsync(wsb + stateStart, 0, stateEnd - stateStart, stream);

  // ---- recurrent loop: 2 phase kernels per step ----
  for (int t = 0; t < S; ++t) {
    int pq = t & 1;
    __half* in0cur[3], *in0nxt[3], *in1cur[3], *in1nxt[3];
    for (int m = 0; m < 3; ++m) {
      in0cur[m] = In0[m] + (size_t)pq * B * 3072;
      in0nxt[m] = In0[m] + (size_t)(pq ^ 1) * B * 3072;
      in1cur[m] = In1[m] + (size_t)pq * B * 2048;
      in1nxt[m] = In1[m] + (size_t)(pq ^ 1) * B * 2048;
    }

    PhaseParams PA;
    for (int m = 0; m < 3; ++m) {
      ModParam& q = PA.m[m];
      q.xseg = X16[m] + (size_t)t * B * FPAD[m];
      q.Kx = FPAD[m];
      q.inseg = in0cur[m];
      q.Kin = 3072;
      q.W = W0[m];
      q.bias = biasB + m * NG;
      q.c = cbuf + (size_t)m * B * H;
      q.dst0 = in1cur[m]; q.off0 = 0;      // -> layer1 input (this step)
      q.dst1 = in0nxt[m]; q.off1 = 2048;   // -> own h0 slot (next step)
      q.dst2 = nullptr;   q.off2 = 0;
      q.feat = nullptr;   q.featoff = 0;
    }
    lstm_phase<<<dim3(1536), 256, 0, stream>>>(PA);

    PhaseParams PB;
    for (int m = 0; m < 3; ++m) {
      ModParam& q = PB.m[m];
      q.xseg = nullptr; q.Kx = 0;
      q.inseg = in1cur[m]; q.Kin = 2048;
      q.W = W1[m];
      q.bias = biasB + (3 + m) * NG;
      q.c = cbuf + (size_t)(3 + m) * B * H;
      q.feat = (t == S - 1) ? featB : nullptr;
      q.featoff = m * H;
      if (m == 0) {        // h1_t -> In0_v[:,0], In0_a[:,0], In1_t[:,1024]
        q.dst0 = in0nxt[1]; q.off0 = 0;
        q.dst1 = in0nxt[2]; q.off1 = 0;
        q.dst2 = in1nxt[0]; q.off2 = 1024;
      } else if (m == 1) { // h1_v -> In0_t[:,0], In0_a[:,1024], In1_v[:,1024]
        q.dst0 = in0nxt[0]; q.off0 = 0;
        q.dst1 = in0nxt[2]; q.off1 = 1024;
        q.dst2 = in1nxt[1]; q.off2 = 1024;
      } else {             // h1_a -> In0_t[:,1024], In0_v[:,1024], In1_a[:,1024]
        q.dst0 = in0nxt[0]; q.off0 = 1024;
        q.dst1 = in0nxt[1]; q.off1 = 1024;
        q.dst2 = in1nxt[2]; q.off2 = 1024;
      }
    }
    lstm_phase<<<dim3(1536), 256, 0, stream>>>(PB);
  }

  final_dot<<<dim3(256), 256, 0, stream>>>(featB, Wd, bd, (float*)d_out);
}

// Round 14
// 9877.535 us; speedup vs baseline: 1.0692x; 1.0692x over previous
//
#include <hip/hip_runtime.h>
#include <hip/hip_fp16.h>
#include <cstdint>
#include <cstddef>

// ---------------------------------------------------------------------------
// Fused cross-modal 2-layer LSTM, B=256, S=128, H=1024, 3 modalities.
// v14 = v7 (best measured: 9886 us, absmax 4.9e-4), restored verbatim.
// Multi-launch structure + counted-vmcnt pipeline: 3-slot A LDS ring (48 KB,
// 3 blocks/CU), stage/loadB issued before a RAW s_barrier with s_waitcnt
// vmcnt(8) (never 0 mid-loop), sched_barrier after. 64x64 block, K-split-4
// across 4 waves, frag-packed B global->VGPR, cross-wave LDS reduction,
// LSTM cell fused in epilogue (4-lane shfl). fp16 MFMA fp32-accum.
//
// 13-round summary: seven structurally distinct K-loops all land at
// 75-80 us/step; binding constraint is the serial per-step 131 MB weight
// stream through the launch-invalidated L2-miss path at ~1.8 TB/s
// (~73 us/step floor). v7 runs at ~90% of that floor. Persistence loses
// (fence invalidation or unsound coherence); fp8 weights blow the error
// budget; occupancy/pipeline-depth/barrier changes are all flat.
// ---------------------------------------------------------------------------

typedef _Float16 half8 __attribute__((ext_vector_type(8)));
typedef float floatx4 __attribute__((ext_vector_type(4)));

__device__ __forceinline__ void gload16(const void* g, void* l) {
  __builtin_amdgcn_global_load_lds(
      (const __attribute__((address_space(1))) void*)g,
      (__attribute__((address_space(3))) void*)l, 16, 0, 0);
}
__device__ __forceinline__ float fsig(float x) {
  return 1.f / (1.f + __expf(-x));
}
__device__ __forceinline__ float ftanhf(float x) {
  x = fminf(15.f, fmaxf(-15.f, x));
  float e = __expf(2.f * x);
  return (e - 1.f) / (e + 1.f);
}

struct ModParam {
  const __half* xseg;   // chunked [Kx/8][256][8] (null if Kx==0)
  const __half* inseg;  // chunked [Kin/8][256][8]
  const __half* W;      // frag-packed [64][nKt][4 wid][4 ni][64 lane][8]
  const float* bias;    // [4096] gate-interleaved (bih+bhh)
  float* c;             // [256][1024] fp32 cell state
  __half* dst0; __half* dst1; __half* dst2;  // chunked h dests (may be null)
  int off0, off1, off2; // column offsets (multiples of 1024)
  __half* feat; int featoff;  // linear [256][3072]; last step only
  int Kx, Kin;
};
struct PhaseParams { ModParam m[3]; };

// C[b,n'] = sum_k In[b,k] * W[n',k];  M=256, N=4096 per modality.
// Block = 64(M) x 64(N); 4 waves K-split a K128 staged tile (wave w takes
// k-quarter w); 4x4 16x16x32 fragments per wave; LDS reduce; fused cell.
// K-loop: 3-slot LDS ring + counted vmcnt + raw barrier (loads stay in
// flight across barriers). grid = 8 xcd-slots * 96 = 768 = 3 blocks/CU.
__global__ __launch_bounds__(256, 3) void lstm_phase(PhaseParams P) {
  const int b_ = blockIdx.x;
  const int xcd = b_ & 7, rnd = b_ >> 3;
  const int pairIdx = xcd * 24 + (rnd >> 2);   // 0..191 = (mod, bn)
  const int mt = rnd & 3;
  const int mod = pairIdx >> 6;
  const int bn = pairIdx & 63;
  const ModParam p = P.m[mod];
  const int nKt = (p.Kx + p.Kin) >> 7;
  const int KxT = p.Kx >> 7;
  const int tid = threadIdx.x;
  const int lane = tid & 63, wid = tid >> 6;
  const int ln = lane & 15, lm = lane >> 4, c4 = lane & 3;

  __shared__ __align__(16) __half smem[3][1024][8];  // 3 x 16 KiB A ring

  floatx4 acc[4][4];
#pragma unroll
  for (int a = 0; a < 4; ++a)
#pragma unroll
    for (int b = 0; b < 4; ++b) acc[a][b] = (floatx4)0.f;

  half8 bvA[4], bvB[4];

  auto stageA = [&](int kt, int buf) {
    const __half* base; int kq0;
    if (kt < KxT) { base = p.xseg;  kq0 = kt * 16; }
    else          { base = p.inseg; kq0 = (kt - KxT) * 16; }
#pragma unroll
    for (int it = 0; it < 4; ++it) {
      int idx = it * 256 + tid;                 // chunk id 0..1023
      int kql = idx >> 6, bl = idx & 63;
      gload16(base + ((size_t)(kq0 + kql) * 256 + mt * 64 + bl) * 8,
              &smem[buf][idx][0]);
    }
  };
  auto loadB = [&](int kt, half8 (&bv)[4]) {
    const __half* src =
        p.W + ((size_t)(bn * nKt + kt) * 4 + wid) * 2048 + lane * 8;
#pragma unroll
    for (int ni = 0; ni < 4; ++ni) bv[ni] = *(const half8*)(src + ni * 512);
  };
  auto compute = [&](int buf, const half8 (&bv)[4]) {
    half8 av[4];
    const int kq = wid * 4 + lm;
#pragma unroll
    for (int mi = 0; mi < 4; ++mi)
      av[mi] = *(const half8*)&smem[buf][kq * 64 + mi * 16 + ln][0];
#pragma unroll
    for (int mi = 0; mi < 4; ++mi)
#pragma unroll
      for (int ni = 0; ni < 4; ++ni)
        acc[mi][ni] = __builtin_amdgcn_mfma_f32_16x16x32_f16(
            av[mi], bv[ni], acc[mi][ni], 0, 0, 0);
  };

  // prologue: tile 0 in flight (8 vmem ops/thread)
  stageA(0, 0);
  loadB(0, bvA);
  int kt = 0;
  while (true) {
    // even sub-iter: compute kt from slot kt%3 with bvA
    if (kt + 1 < nKt) {
      stageA(kt + 1, (kt + 1) % 3);
      loadB(kt + 1, bvB);
      asm volatile("s_waitcnt vmcnt(8)" ::: "memory");
    } else {
      asm volatile("s_waitcnt vmcnt(0)" ::: "memory");
    }
    __builtin_amdgcn_s_barrier();
    __builtin_amdgcn_sched_barrier(0);
    compute(kt % 3, bvA);
    if (++kt >= nKt) break;
    // odd sub-iter: compute kt from slot kt%3 with bvB
    if (kt + 1 < nKt) {
      stageA(kt + 1, (kt + 1) % 3);
      loadB(kt + 1, bvA);
      asm volatile("s_waitcnt vmcnt(8)" ::: "memory");
    } else {
      asm volatile("s_waitcnt vmcnt(0)" ::: "memory");
    }
    __builtin_amdgcn_s_barrier();
    __builtin_amdgcn_sched_barrier(0);
    compute(kt % 3, bvB);
    if (++kt >= nKt) break;
  }
  __syncthreads();  // all compute done before LDS is reused for reduction

  // ---- cross-wave K-reduction (acc summed over the 4 waves) ----
  // rbuf[h(2)][ni(4)][w(4)][lane(64)] of floatx4 = 32 KiB (reuses smem).
  floatx4* rbuf = (floatx4*)&smem[0][0][0];
  auto slot = [&](int h, int ni, int w) {
    return ((h * 4 + ni) * 4 + w) * 64 + lane;
  };
  floatx4 own[4];
#pragma unroll
  for (int ni = 0; ni < 4; ++ni) {
    rbuf[slot(0, ni, wid)] = acc[0][ni];
    rbuf[slot(1, ni, wid)] = acc[1][ni];
  }
  __syncthreads();
  if (wid == 0) {
#pragma unroll
    for (int ni = 0; ni < 4; ++ni)
      own[ni] = acc[0][ni] + rbuf[slot(0, ni, 1)] + rbuf[slot(0, ni, 2)] +
                rbuf[slot(0, ni, 3)];
  } else if (wid == 1) {
#pragma unroll
    for (int ni = 0; ni < 4; ++ni)
      own[ni] = acc[1][ni] + rbuf[slot(1, ni, 0)] + rbuf[slot(1, ni, 2)] +
                rbuf[slot(1, ni, 3)];
  }
  __syncthreads();
#pragma unroll
  for (int ni = 0; ni < 4; ++ni) {
    rbuf[slot(0, ni, wid)] = acc[2][ni];
    rbuf[slot(1, ni, wid)] = acc[3][ni];
  }
  __syncthreads();
  if (wid == 2) {
#pragma unroll
    for (int ni = 0; ni < 4; ++ni)
      own[ni] = acc[2][ni] + rbuf[slot(0, ni, 0)] + rbuf[slot(0, ni, 1)] +
                rbuf[slot(0, ni, 3)];
  } else if (wid == 3) {
#pragma unroll
    for (int ni = 0; ni < 4; ++ni)
      own[ni] = acc[3][ni] + rbuf[slot(1, ni, 0)] + rbuf[slot(1, ni, 1)] +
                rbuf[slot(1, ni, 2)];
  }

  // ---- fused LSTM cell epilogue (wave owns M-rows [wid*16, wid*16+16)) ----
#pragma unroll
  for (int ni = 0; ni < 4; ++ni) {
    const int ncol = bn * 64 + ni * 16 + ln;
    const float bia = p.bias[ncol];
    const int j = ncol >> 2;
#pragma unroll
    for (int r = 0; r < 4; ++r) {
      float v = own[ni][r] + bia;
      float g1 = __shfl_xor(v, 1);
      float g2 = __shfl_xor(v, 2);
      float g3 = __shfl_xor(v, 3);
      int m0 = c4, m1 = c4 ^ 1, m2 = c4 ^ 2, m3 = c4 ^ 3;
      float zi = m0 == 0 ? v : (m0 == 1 ? g1 : (m0 == 2 ? g2 : g3));
      float zf = m1 == 0 ? v : (m1 == 1 ? g1 : (m1 == 2 ? g2 : g3));
      float zg = m2 == 0 ? v : (m2 == 1 ? g1 : (m2 == 2 ? g2 : g3));
      float zo = m3 == 0 ? v : (m3 == 1 ? g1 : (m3 == 2 ? g2 : g3));
      const int b = mt * 64 + wid * 16 + lm * 4 + r;
      float cp = p.c[b * 1024 + j];
      float cn = fsig(zf) * cp + fsig(zi) * ftanhf(zg);
      float hn = fsig(zo) * ftanhf(cn);
      __half h16 = __float2half(hn);
      if (c4 == 0) {
        if (p.dst0) {
          int col = p.off0 + j;
          p.dst0[(size_t)(col >> 3) * 2048 + b * 8 + (col & 7)] = h16;
        }
      } else if (c4 == 1) {
        if (p.dst1) {
          int col = p.off1 + j;
          p.dst1[(size_t)(col >> 3) * 2048 + b * 8 + (col & 7)] = h16;
        }
      } else if (c4 == 2) {
        if (p.dst2) {
          int col = p.off2 + j;
          p.dst2[(size_t)(col >> 3) * 2048 + b * 8 + (col & 7)] = h16;
        }
      } else {
        p.c[b * 1024 + j] = cn;
        if (p.feat) p.feat[(size_t)b * 3072 + p.featoff + j] = h16;
      }
    }
  }
}

// Repack weights fp32->fp16 into MFMA-fragment order:
// dst[((nt*nKt + kt)*4 + wid)*2048 + ni*512 + lane*8 + e] = W[n][k], where
// n = nt*64 + ni*16 + (lane&15) (gate-interleaved src), k = kt*128 + wid*32
// + (lane>>4)*8 + e, columns = [x pad fpad | ih-h (hih) | hh 1024].
__global__ void pack_w(__half* dst, const float* Wih, const float* Whh,
                       float* bdst, const float* bih, const float* bhh,
                       int f, int fpad, int hih, int Ktot) {
  long long i = (long long)blockIdx.x * 256 + threadIdx.x;
  long long tot = (long long)4096 * Ktot;
  const int nKt = Ktot >> 7;
  if (i < tot) {
    int q = (int)(i >> 11);
    int wid = q & 3;
    int p2 = q >> 2;
    int ktile = p2 % nKt, nt = p2 / nKt;
    int r = (int)(i & 2047);
    int ni = r >> 9, lane = (r >> 3) & 63, e = r & 7;
    int n = nt * 64 + ni * 16 + (lane & 15);
    int nsrc = (n & 3) * 1024 + (n >> 2);
    int k = ktile * 128 + wid * 32 + (lane >> 4) * 8 + e;
    float v;
    if (k < fpad)
      v = (k < f) ? Wih[(size_t)nsrc * (f + hih) + k] : 0.f;
    else if (k < fpad + hih)
      v = Wih[(size_t)nsrc * (f + hih) + f + (k - fpad)];
    else
      v = Whh[(size_t)nsrc * 1024 + (k - fpad - hih)];
    dst[i] = __float2half(v);
  }
  if (i < 4096) {
    int nsrc = ((int)i & 3) * 1024 + ((int)i >> 2);
    bdst[i] = bih[nsrc] + bhh[nsrc];
  }
}

// x [B=256][S=128][f] fp32 -> chunked fp16 [S][fpad/8][256][8], zero-padded.
__global__ void pack_x(__half* dst, const float* x, int f, int fpad) {
  long long i = (long long)blockIdx.x * 256 + threadIdx.x;
  long long tot = (long long)128 * 256 * fpad;
  if (i >= tot) return;
  int e = (int)(i & 7);
  long long u = i >> 3;
  int b = (int)(u & 255);
  long long v = u >> 8;
  int nq = fpad >> 3;
  int kq = (int)(v % nq);
  int t = (int)(v / nq);
  int k = kq * 8 + e;
  dst[i] = (k < f) ? __float2half(x[((size_t)b * 128 + t) * f + k])
                   : __float2half(0.f);
}

// out[b] = feat[b,:] . Wd + bd
__global__ void final_dot(const __half* feat, const float* Wd, const float* bd,
                          float* out) {
  int b = blockIdx.x, tid = threadIdx.x;
  float s = 0.f;
  for (int j = tid; j < 3072; j += 256)
    s += __half2float(feat[(size_t)b * 3072 + j]) * Wd[j];
  __shared__ float red[256];
  red[tid] = s;
  __syncthreads();
  for (int o = 128; o > 0; o >>= 1) {
    if (tid < o) red[tid] += red[tid + o];
    __syncthreads();
  }
  if (tid == 0) out[b] = red[0] + bd[0];
}

extern "C" void kernel_launch(void* const* d_in, const int* in_sizes, int n_in,
                              void* d_out, int out_size, void* d_ws, size_t ws_size,
                              hipStream_t stream) {
  const int B = 256, S = 128, H = 1024, NG = 4096;
  const int FRAW[3] = {300, 35, 74};
  const int FPAD[3] = {384, 128, 128};  // multiples of 128

  const float* xin[3] = {(const float*)d_in[0], (const float*)d_in[1],
                         (const float*)d_in[2]};
  const float *Wih0[3], *Whh0[3], *bih0[3], *bhh0[3];
  const float *Wih1[3], *Whh1[3], *bih1[3], *bhh1[3];
  for (int m = 0; m < 3; ++m) {
    int bidx = 3 + m * 8;
    Wih0[m] = (const float*)d_in[bidx + 0];
    Whh0[m] = (const float*)d_in[bidx + 1];
    bih0[m] = (const float*)d_in[bidx + 2];
    bhh0[m] = (const float*)d_in[bidx + 3];
    Wih1[m] = (const float*)d_in[bidx + 4];
    Whh1[m] = (const float*)d_in[bidx + 5];
    bih1[m] = (const float*)d_in[bidx + 6];
    bhh1[m] = (const float*)d_in[bidx + 7];
  }
  const float* Wd = (const float*)d_in[27];
  const float* bd = (const float*)d_in[28];

  uint8_t* wsb = (uint8_t*)d_ws;
  size_t off = 0;
  auto alloc = [&](size_t bytes) -> void* {
    void* p = wsb + off;
    off += (bytes + 255) & ~(size_t)255;
    return p;
  };

  __half* W0[3];
  __half* W1[3];
  int K0[3];
  for (int m = 0; m < 3; ++m) {
    K0[m] = FPAD[m] + 3 * H;
    W0[m] = (__half*)alloc((size_t)NG * K0[m] * 2);
  }
  for (int m = 0; m < 3; ++m) W1[m] = (__half*)alloc((size_t)NG * 2 * H * 2);
  float* biasB = (float*)alloc((size_t)6 * NG * 4);
  __half* X16[3];
  for (int m = 0; m < 3; ++m)
    X16[m] = (__half*)alloc((size_t)S * B * FPAD[m] * 2);
  size_t stateStart = off;
  __half* In0[3];
  __half* In1[3];
  for (int m = 0; m < 3; ++m) In0[m] = (__half*)alloc((size_t)2 * B * 3072 * 2);
  for (int m = 0; m < 3; ++m) In1[m] = (__half*)alloc((size_t)2 * B * 2048 * 2);
  float* cbuf = (float*)alloc((size_t)6 * B * H * 4);
  size_t stateEnd = off;
  __half* featB = (__half*)alloc((size_t)B * 3072 * 2);

  if (off > ws_size) return;

  // ---- one-time prep (every call; deterministic) ----
  for (int m = 0; m < 3; ++m) {
    long long tot0 = (long long)NG * K0[m];
    pack_w<<<dim3((unsigned)((tot0 + 255) / 256)), 256, 0, stream>>>(
        W0[m], Wih0[m], Whh0[m], biasB + m * NG, bih0[m], bhh0[m],
        FRAW[m], FPAD[m], 2 * H, K0[m]);
    long long tot1 = (long long)NG * 2 * H;
    pack_w<<<dim3((unsigned)((tot1 + 255) / 256)), 256, 0, stream>>>(
        W1[m], Wih1[m], Whh1[m], biasB + (3 + m) * NG, bih1[m], bhh1[m],
        0, 0, H, 2 * H);
    long long totx = (long long)S * B * FPAD[m];
    pack_x<<<dim3((unsigned)((totx + 255) / 256)), 256, 0, stream>>>(
        X16[m], xin[m], FRAW[m], FPAD[m]);
  }
  hipMemsetAsync(wsb + stateStart, 0, stateEnd - stateStart, stream);

  // ---- recurrent loop: 2 phase kernels per step ----
  for (int t = 0; t < S; ++t) {
    int pq = t & 1;
    __half* in0cur[3], *in0nxt[3], *in1cur[3], *in1nxt[3];
    for (int m = 0; m < 3; ++m) {
      in0cur[m] = In0[m] + (size_t)pq * B * 3072;
      in0nxt[m] = In0[m] + (size_t)(pq ^ 1) * B * 3072;
      in1cur[m] = In1[m] + (size_t)pq * B * 2048;
      in1nxt[m] = In1[m] + (size_t)(pq ^ 1) * B * 2048;
    }

    PhaseParams PA;
    for (int m = 0; m < 3; ++m) {
      ModParam& q = PA.m[m];
      q.xseg = X16[m] + (size_t)t * B * FPAD[m];
      q.Kx = FPAD[m];
      q.inseg = in0cur[m];
      q.Kin = 3072;
      q.W = W0[m];
      q.bias = biasB + m * NG;
      q.c = cbuf + (size_t)m * B * H;
      q.dst0 = in1cur[m]; q.off0 = 0;      // -> layer1 input (this step)
      q.dst1 = in0nxt[m]; q.off1 = 2048;   // -> own h0 slot (next step)
      q.dst2 = nullptr;   q.off2 = 0;
      q.feat = nullptr;   q.featoff = 0;
    }
    lstm_phase<<<dim3(768), 256, 0, stream>>>(PA);

    PhaseParams PB;
    for (int m = 0; m < 3; ++m) {
      ModParam& q = PB.m[m];
      q.xseg = nullptr; q.Kx = 0;
      q.inseg = in1cur[m]; q.Kin = 2048;
      q.W = W1[m];
      q.bias = biasB + (3 + m) * NG;
      q.c = cbuf + (size_t)(3 + m) * B * H;
      q.feat = (t == S - 1) ? featB : nullptr;
      q.featoff = m * H;
      if (m == 0) {        // h1_t -> In0_v[:,0], In0_a[:,0], In1_t[:,1024]
        q.dst0 = in0nxt[1]; q.off0 = 0;
        q.dst1 = in0nxt[2]; q.off1 = 0;
        q.dst2 = in1nxt[0]; q.off2 = 1024;
      } else if (m == 1) { // h1_v -> In0_t[:,0], In0_a[:,1024], In1_v[:,1024]
        q.dst0 = in0nxt[0]; q.off0 = 0;
        q.dst1 = in0nxt[2]; q.off1 = 1024;
        q.dst2 = in1nxt[1]; q.off2 = 1024;
      } else {             // h1_a -> In0_t[:,1024], In0_v[:,1024], In1_a[:,1024]
        q.dst0 = in0nxt[0]; q.off0 = 1024;
        q.dst1 = in0nxt[1]; q.off1 = 1024;
        q.dst2 = in1nxt[2]; q.off2 = 1024;
      }
    }
    lstm_phase<<<dim3(768), 256, 0, stream>>>(PB);
  }

  final_dot<<<dim3(256), 256, 0, stream>>>(featB, Wd, bd, (float*)d_out);
}